// Round 1
// baseline (1190.287 us; speedup 1.0000x reference)
//
#include <hip/hip_runtime.h>
#include <hip/hip_bf16.h>
#include <stdint.h>

#define NPROT 19000
#define NDRUG 4000
#define NCELL 16
#define BATCH 4096
#define NEDGE 40000
#define L0 2048
#define L1DIM 1024
#define INDIM 38032
#define HALFDIM 19016

typedef float f32x4 __attribute__((ext_vector_type(4)));
typedef short s16x8 __attribute__((ext_vector_type(8)));

__global__ void zero_int_kernel(int* __restrict__ p, int n) {
    int i = blockIdx.x * 256 + threadIdx.x;
    if (i < n) p[i] = 0;
}

__global__ void hist_kernel(const int* __restrict__ prot, int* __restrict__ hist) {
    int e = blockIdx.x * 256 + threadIdx.x;
    if (e < NEDGE) atomicAdd(&hist[prot[e]], 1);
}

__global__ __launch_bounds__(256) void scan_kernel(const int* __restrict__ hist, int* __restrict__ row_ptr) {
    __shared__ int part[256];
    int t = threadIdx.x;
    const int CH = (NPROT + 255) / 256;  // 75
    int s = 0;
    for (int j = 0; j < CH; ++j) {
        int idx = t * CH + j;
        if (idx < NPROT) s += hist[idx];
    }
    part[t] = s;
    __syncthreads();
    if (t == 0) {
        int run = 0;
        for (int i = 0; i < 256; ++i) { int v = part[i]; part[i] = run; run += v; }
    }
    __syncthreads();
    int run = part[t];
    for (int j = 0; j < CH; ++j) {
        int idx = t * CH + j;
        if (idx < NPROT) { row_ptr[idx] = run; run += hist[idx]; }
    }
    if (t == 255) row_ptr[NPROT] = NEDGE;
}

__global__ void scatter_kernel(const int* __restrict__ prot, const int* __restrict__ drug,
                               const int* __restrict__ row_ptr, int* __restrict__ cnt,
                               int* __restrict__ col) {
    int e = blockIdx.x * 256 + threadIdx.x;
    if (e < NEDGE) {
        int p = prot[e];
        int pos = row_ptr[p] + atomicAdd(&cnt[p], 1);
        col[pos] = drug[e];
    }
}

// reference uses .set(1.0): duplicate (drug,prot) edges count once -> mark dups -1
__global__ void dedup_kernel(const int* __restrict__ row_ptr, int* __restrict__ col) {
    int p = blockIdx.x * 256 + threadIdx.x;
    if (p < NPROT) {
        int beg = row_ptr[p], end = row_ptr[p + 1];
        for (int i = beg + 1; i < end; ++i) {
            int d = col[i];
            for (int j = beg; j < i; ++j)
                if (col[j] == d) { col[i] = -1; break; }
        }
    }
}

// BASE[c][ch] = b0[ch] + W0[ch, 19000+c] + W0[ch, 38016+c]
__global__ void base_kernel(const float* __restrict__ W0, const float* __restrict__ b0,
                            float* __restrict__ BASE) {
    int i = blockIdx.x * 256 + threadIdx.x;
    if (i < NCELL * L0) {
        int c = i >> 11, ch = i & 2047;
        const float* wr = W0 + (size_t)ch * INDIM;
        BASE[(size_t)c * L0 + ch] = b0[ch] + wr[NPROT + c] + wr[HALFDIM + NPROT + c];
    }
}

// SA[d][ch] = sum over proteins of drug d of W0[ch, p]   (blockIdx.y=0)
// SB[d][ch] = same over W0[ch, 19016+p]                  (blockIdx.y=1)
// block owns 4 channels; streams the W0 half-row coalesced; LDS drug accumulator.
__global__ __launch_bounds__(256) void drug_sum_kernel(const float* __restrict__ W0,
                                                       const int* __restrict__ row_ptr,
                                                       const int* __restrict__ col,
                                                       float* __restrict__ SA,
                                                       float* __restrict__ SB) {
    __shared__ float acc[4][NDRUG];  // 64000 B
    int t = threadIdx.x;
    int hb = blockIdx.y;
    int ch0 = blockIdx.x * 4;
    for (int i = t; i < 4 * NDRUG; i += 256) ((float*)acc)[i] = 0.f;
    __syncthreads();
    size_t colbase = (size_t)hb * HALFDIM;
    for (int ch = 0; ch < 4; ++ch) {
        const float* wrow = W0 + (size_t)(ch0 + ch) * INDIM + colbase;
        for (int p0 = t * 4; p0 < NPROT; p0 += 1024) {
            float4 w = *(const float4*)(wrow + p0);
            const float* wv = (const float*)&w;
#pragma unroll
            for (int j = 0; j < 4; ++j) {
                int p = p0 + j;
                int beg = row_ptr[p], end = row_ptr[p + 1];
                for (int e = beg; e < end; ++e) {
                    int d = col[e];
                    if (d >= 0) atomicAdd(&acc[ch][d], wv[j]);
                }
            }
        }
    }
    __syncthreads();
    float* dst = hb ? SB : SA;
    for (int d = t; d < NDRUG; d += 256) {
        float4 v;
        v.x = acc[0][d]; v.y = acc[1][d]; v.z = acc[2][d]; v.w = acc[3][d];
        *(float4*)(dst + (size_t)d * L0 + ch0) = v;
    }
}

__global__ void cvtw1_kernel(const float* __restrict__ W1, __hip_bfloat16* __restrict__ W1b) {
    int i = blockIdx.x * 256 + threadIdx.x;  // one float4 each
    const int n = L1DIM * L0 / 4;
    if (i < n) {
        float4 v = ((const float4*)W1)[i];
        union { ushort4 u; __hip_bfloat16 h[4]; } pk;
        pk.h[0] = __float2bfloat16(v.x);
        pk.h[1] = __float2bfloat16(v.y);
        pk.h[2] = __float2bfloat16(v.z);
        pk.h[3] = __float2bfloat16(v.w);
        ((ushort4*)W1b)[i] = pk.u;
    }
}

// h1[b]        = relu(BASE[c] + SA[d1] + SB[d2])  (x1)
// h1[4096+b]   = relu(BASE[c] + SA[d2] + SB[d1])  (x2)
__global__ __launch_bounds__(256) void build_h_kernel(const int* __restrict__ dp,
                                                      const int* __restrict__ cl,
                                                      const float* __restrict__ SA,
                                                      const float* __restrict__ SB,
                                                      const float* __restrict__ BASE,
                                                      __hip_bfloat16* __restrict__ h1) {
    int b = blockIdx.x;
    int d1 = dp[2 * b], d2 = dp[2 * b + 1], c = cl[b];
    const float* bs = BASE + (size_t)c * L0;
    const float* a1 = SA + (size_t)d1 * L0;
    const float* a2 = SA + (size_t)d2 * L0;
    const float* s1 = SB + (size_t)d1 * L0;
    const float* s2 = SB + (size_t)d2 * L0;
    for (int ch = threadIdx.x * 4; ch < L0; ch += 1024) {
        float4 vb = *(const float4*)(bs + ch);
        float4 va1 = *(const float4*)(a1 + ch);
        float4 va2 = *(const float4*)(a2 + ch);
        float4 vs1 = *(const float4*)(s1 + ch);
        float4 vs2 = *(const float4*)(s2 + ch);
        union { ushort4 u; __hip_bfloat16 h[4]; } p1, p2;
        const float* fb = (const float*)&vb;
        const float* fa1 = (const float*)&va1;
        const float* fa2 = (const float*)&va2;
        const float* fs1 = (const float*)&vs1;
        const float* fs2 = (const float*)&vs2;
#pragma unroll
        for (int j = 0; j < 4; ++j) {
            float z1 = fb[j] + fa1[j] + fs2[j];
            float z2 = fb[j] + fa2[j] + fs1[j];
            p1.h[j] = __float2bfloat16(fmaxf(z1, 0.f));
            p2.h[j] = __float2bfloat16(fmaxf(z2, 0.f));
        }
        *(ushort4*)((__hip_bfloat16*)h1 + (size_t)b * L0 + ch) = p1.u;
        *(ushort4*)((__hip_bfloat16*)h1 + (size_t)(BATCH + b) * L0 + ch) = p2.u;
    }
}

// C = relu(A @ B^T + bias), A: MxK bf16, B: NxK bf16 (W1), C: MxN bf16
#define BM 128
#define BN 128
#define BKK 32
__global__ __launch_bounds__(256) void gemm_kernel(const __hip_bfloat16* __restrict__ A,
                                                   const __hip_bfloat16* __restrict__ B,
                                                   const float* __restrict__ bias,
                                                   __hip_bfloat16* __restrict__ C,
                                                   int M, int N, int K) {
    __shared__ __hip_bfloat16 As[BM * BKK];
    __shared__ __hip_bfloat16 Bs[BN * BKK];
    int t = threadIdx.x;
    int ntiles = N / BN;
    int bx = blockIdx.x % ntiles;
    int by = blockIdx.x / ntiles;
    int brow = by * BM, bcol = bx * BN;
    int w = t >> 6, l = t & 63;
    int wr = w >> 1, wc = w & 1;
    f32x4 acc[4][4] = {};
    int row = l & 15, ko = (l >> 4) * 8;
    for (int k0 = 0; k0 < K; k0 += BKK) {
#pragma unroll
        for (int i = 0; i < 2; ++i) {
            int idx = i * 256 + t;
            int r = idx >> 2, cb = (idx & 3) * 8;
            __builtin_amdgcn_global_load_lds(
                (const __attribute__((address_space(1))) void*)(A + (size_t)(brow + r) * K + k0 + cb),
                (__attribute__((address_space(3))) void*)(&As[idx * 8]), 16, 0, 0);
            __builtin_amdgcn_global_load_lds(
                (const __attribute__((address_space(1))) void*)(B + (size_t)(bcol + r) * K + k0 + cb),
                (__attribute__((address_space(3))) void*)(&Bs[idx * 8]), 16, 0, 0);
        }
        __syncthreads();
        s16x8 af[4], bfr[4];
#pragma unroll
        for (int m = 0; m < 4; ++m)
            af[m] = *(const s16x8*)(&As[(wr * 64 + m * 16 + row) * BKK + ko]);
#pragma unroll
        for (int n = 0; n < 4; ++n)
            bfr[n] = *(const s16x8*)(&Bs[(wc * 64 + n * 16 + row) * BKK + ko]);
#pragma unroll
        for (int m = 0; m < 4; ++m)
#pragma unroll
            for (int n = 0; n < 4; ++n)
                acc[m][n] = __builtin_amdgcn_mfma_f32_16x16x32_bf16(af[m], bfr[n], acc[m][n], 0, 0, 0);
        __syncthreads();
    }
    int cr = (l >> 4) * 4;
    int cc = l & 15;
#pragma unroll
    for (int m = 0; m < 4; ++m)
#pragma unroll
        for (int n = 0; n < 4; ++n) {
#pragma unroll
            for (int j = 0; j < 4; ++j) {
                int grow = brow + wr * 64 + m * 16 + cr + j;
                int gcol = bcol + wc * 64 + n * 16 + cc;
                float v = acc[m][n][j] + bias[gcol];
                C[(size_t)grow * N + gcol] = __float2bfloat16(fmaxf(v, 0.f));
            }
        }
}

// out[r] = b2 + sum_o h2[r][o] * W2[o]
__global__ __launch_bounds__(128) void out_kernel(const __hip_bfloat16* __restrict__ h2,
                                                  const float* __restrict__ W2,
                                                  const float* __restrict__ b2,
                                                  float* __restrict__ out) {
    int r = blockIdx.x;
    int t = threadIdx.x;
    union { uint4 u; __hip_bfloat16 h[8]; } pk;
    pk.u = *(const uint4*)(h2 + (size_t)r * L1DIM + t * 8);
    float s = 0.f;
#pragma unroll
    for (int j = 0; j < 8; ++j) s += __bfloat162float(pk.h[j]) * W2[t * 8 + j];
    for (int o = 32; o > 0; o >>= 1) s += __shfl_down(s, o);
    __shared__ float red[2];
    if ((t & 63) == 0) red[t >> 6] = s;
    __syncthreads();
    if (t == 0) out[r] = red[0] + red[1] + b2[0];
}

extern "C" void kernel_launch(void* const* d_in, const int* in_sizes, int n_in,
                              void* d_out, int out_size, void* d_ws, size_t ws_size,
                              hipStream_t stream) {
    const int* drug_pairs = (const int*)d_in[0];
    const int* cell_lines = (const int*)d_in[1];
    const int* dpi_drug = (const int*)d_in[2];
    const int* dpi_prot = (const int*)d_in[3];
    const float* W0 = (const float*)d_in[4];
    const float* b0 = (const float*)d_in[5];
    const float* W1 = (const float*)d_in[6];
    const float* b1 = (const float*)d_in[7];
    const float* W2 = (const float*)d_in[8];
    const float* b2 = (const float*)d_in[9];
    float* out = (float*)d_out;

    char* ws = (char*)d_ws;
    size_t off = 0;
    auto alloc = [&](size_t bytes) {
        char* p = ws + off;
        off += (bytes + 255) & ~(size_t)255;
        return p;
    };
    float* SA = (float*)alloc((size_t)NDRUG * L0 * 4);
    float* SB = (float*)alloc((size_t)NDRUG * L0 * 4);
    float* BASE = (float*)alloc((size_t)NCELL * L0 * 4);
    __hip_bfloat16* W1b = (__hip_bfloat16*)alloc((size_t)L1DIM * L0 * 2);
    __hip_bfloat16* h1 = (__hip_bfloat16*)alloc((size_t)2 * BATCH * L0 * 2);
    __hip_bfloat16* h2 = (__hip_bfloat16*)alloc((size_t)2 * BATCH * L1DIM * 2);
    int* hist = (int*)alloc((size_t)NPROT * 4);
    int* cnt = (int*)alloc((size_t)NPROT * 4);
    int* row_ptr = (int*)alloc((size_t)(NPROT + 1) * 4);
    int* col = (int*)alloc((size_t)NEDGE * 4);

    zero_int_kernel<<<(NPROT + 255) / 256, 256, 0, stream>>>(hist, NPROT);
    zero_int_kernel<<<(NPROT + 255) / 256, 256, 0, stream>>>(cnt, NPROT);
    hist_kernel<<<(NEDGE + 255) / 256, 256, 0, stream>>>(dpi_prot, hist);
    scan_kernel<<<1, 256, 0, stream>>>(hist, row_ptr);
    scatter_kernel<<<(NEDGE + 255) / 256, 256, 0, stream>>>(dpi_prot, dpi_drug, row_ptr, cnt, col);
    dedup_kernel<<<(NPROT + 255) / 256, 256, 0, stream>>>(row_ptr, col);
    base_kernel<<<(NCELL * L0 + 255) / 256, 256, 0, stream>>>(W0, b0, BASE);
    drug_sum_kernel<<<dim3(L0 / 4, 2), 256, 0, stream>>>(W0, row_ptr, col, SA, SB);
    cvtw1_kernel<<<(L1DIM * L0 / 4 + 255) / 256, 256, 0, stream>>>(W1, W1b);
    build_h_kernel<<<BATCH, 256, 0, stream>>>(drug_pairs, cell_lines, SA, SB, BASE, h1);
    gemm_kernel<<<(2 * BATCH / BM) * (L1DIM / BN), 256, 0, stream>>>(h1, W1b, b1, h2,
                                                                     2 * BATCH, L1DIM, L0);
    out_kernel<<<2 * BATCH, 128, 0, stream>>>(h2, W2, b2, out);
}